// Round 4
// baseline (329.218 us; speedup 1.0000x reference)
//
#include <hip/hip_runtime.h>
#include <hip/hip_bf16.h>

// SCNN round 4: round-3 conv pipeline + restructured MLP split-K.
//  - conv: LDS-staged dbuf MFMA GEMM (BM=128 BN=128 BK=64, hi/lo stacked M=512,
//    split-K=2, XOR-swizzle via pre-swizzled global source) -- unchanged
//  - MLP: k_mlp2 -- 64 h-cols x 32 m per block, LDS X-chunk (broadcast reads),
//    W read exactly once, unroll-8 k-loop for 8 outstanding loads/thread

#define B_    32
#define S_    8
#define BS_   256
#define F_    4
#define IN_   8192
#define H_    1024
#define OUT_  256

#define L_TOT  25165824LL     // 2048^2 + 4096^2 + 2048^2
#define LOFF1  4194304LL
#define LOFF2  20971520LL

typedef __attribute__((ext_vector_type(8)))  short bf16x8;
typedef __attribute__((ext_vector_type(4)))  short short4v;
typedef __attribute__((ext_vector_type(16))) float f32x16;

typedef const __attribute__((address_space(1))) void* gas_ptr;
typedef __attribute__((address_space(3))) void* las_ptr;

__device__ __forceinline__ void gload16(const void* g, void* s) {
    __builtin_amdgcn_global_load_lds((gas_ptr)g, (las_ptr)s, 16, 0, 0);
}

__device__ __forceinline__ unsigned short rne_bf16(float f) {
    unsigned int u = __builtin_bit_cast(unsigned int, f);
    u += 0x7FFFu + ((u >> 16) & 1u);
    return (unsigned short)(u >> 16);
}

// ---------------- P/M from Wc ----------------
__global__ void k_prep(const float* __restrict__ Wc0, const float* __restrict__ Wc1,
                       const float* __restrict__ Wc2, float* __restrict__ PM) {
    int idx = blockIdx.x * 256 + threadIdx.x;
    if (idx >= 2 * IN_) return;
    int l = idx / IN_, n = idx % IN_;
    const float* Wc; int nb, j;
    if (n < 2048)      { Wc = Wc0; nb = 2048; j = n;        }
    else if (n < 6144) { Wc = Wc1; nb = 4096; j = n - 2048; }
    else               { Wc = Wc2; nb = 2048; j = n - 6144; }
    float p = 0.f, m = 0.f;
    #pragma unroll
    for (int f = 0; f < F_; ++f) {
        float w = Wc[(l * F_ + f) * nb + j];
        p += fmaxf(w, 0.f);
        m += fmaxf(-w, 0.f);
    }
    PM[(l * 2 + 0) * IN_ + n] = p;
    PM[(l * 2 + 1) * IN_ + n] = m;
}

// ---------------- L f32 -> bf16 (concat) ----------------
__global__ void k_cvtL(const float* __restrict__ L0, const float* __restrict__ L1,
                       const float* __restrict__ L2, unsigned short* __restrict__ Lb) {
    long long e = ((long long)blockIdx.x * 256 + threadIdx.x) * 4;
    if (e >= L_TOT) return;
    const float* src; long long off;
    if (e < LOFF1)      { src = L0; off = 0; }
    else if (e < LOFF2) { src = L1; off = LOFF1; }
    else                { src = L2; off = LOFF2; }
    float4 v = *(const float4*)(src + (e - off));
    short4v o;
    o.x = (short)rne_bf16(v.x); o.y = (short)rne_bf16(v.y);
    o.z = (short)rne_bf16(v.z); o.w = (short)rne_bf16(v.w);
    *(short4v*)(Lb + e) = o;
}

// ---------------- xs -> stacked hi/lo bf16 [512][8192] ----------------
__global__ void k_splitX(const float* __restrict__ x0, const float* __restrict__ x1,
                         const float* __restrict__ x2,
                         unsigned short* __restrict__ Xhi, unsigned short* __restrict__ Xlo) {
    int e = (blockIdx.x * 256 + threadIdx.x) * 4;
    int m = e >> 13, c = e & 8191;
    const float* src; int n, c0;
    if (c < 2048)      { src = x0; n = 2048; c0 = c; }
    else if (c < 6144) { src = x1; n = 4096; c0 = c - 2048; }
    else               { src = x2; n = 2048; c0 = c - 6144; }
    float4 v = *(const float4*)(src + (size_t)m * n + c0);
    float a[4] = {v.x, v.y, v.z, v.w};
    short hv[4], lv[4];
    #pragma unroll
    for (int i = 0; i < 4; ++i) {
        unsigned short hb = rne_bf16(a[i]);
        float hf = __builtin_bit_cast(float, (unsigned int)hb << 16);
        hv[i] = (short)hb;
        lv[i] = (short)rne_bf16(a[i] - hf);
    }
    short4v h = {hv[0], hv[1], hv[2], hv[3]};
    short4v l = {lv[0], lv[1], lv[2], lv[3]};
    *(short4v*)(Xhi + (size_t)m * IN_ + c) = h;
    *(short4v*)(Xlo + (size_t)m * IN_ + c) = l;
}

// ---------------- MFMA GEMM: pf[sk][512][8192] partial = Astk . Lb^T ----------------
__global__ __launch_bounds__(256, 2) void k_gemm(
    const unsigned short* __restrict__ Astk,   // [512][8192] stacked hi/lo
    const unsigned short* __restrict__ Lb,     // concat bf16 L
    float* __restrict__ pf)                    // [2][512][8192]
{
    __shared__ __attribute__((aligned(16))) unsigned short ldsA[2][128 * 64];
    __shared__ __attribute__((aligned(16))) unsigned short ldsB[2][128 * 64];

    const int bx = blockIdx.x;
    const int sk = bx & 1, t = bx >> 1;
    int n_, noff, mt, nt; long long loff;
    if (t < 64)       { mt = t >> 4;         nt = t & 15;        n_ = 2048; noff = 0;    loff = 0;     }
    else if (t < 192) { int u = t - 64;  mt = u >> 5; nt = u & 31; n_ = 4096; noff = 2048; loff = LOFF1; }
    else              { int u = t - 192; mt = u >> 4; nt = u & 15; n_ = 2048; noff = 6144; loff = LOFF2; }

    const int tid = threadIdx.x, l = tid & 63, w = tid >> 6;
    const int n2 = n_ >> 1, k0 = sk * n2, iters = n2 >> 6;

    const int srow = w * 32 + (l >> 3);
    const int cswz = ((l & 7) ^ (l >> 3)) << 3;   // ushort offset
    const unsigned short* gA = Astk + (size_t)(mt * 128 + srow) * IN_ + noff + k0 + cswz;
    const unsigned short* gB = Lb + loff + (size_t)(nt * 128 + srow) * n_ + k0 + cswz;

    const int l31 = l & 31, lh = l >> 5, l7 = l31 & 7;
    const int wm = w >> 1, wn = w & 1;
    const int arow = (wm * 64 + l31) * 64;
    const int brow = (wn * 64 + l31) * 64;

    f32x16 a00, a01, a10, a11;
    #pragma unroll
    for (int r = 0; r < 16; ++r) { a00[r] = 0.f; a01[r] = 0.f; a10[r] = 0.f; a11[r] = 0.f; }

    #pragma unroll
    for (int q = 0; q < 4; ++q) {
        gload16(gA + (size_t)q * 8 * IN_, &ldsA[0][(w * 32 + q * 8) * 64]);
        gload16(gB + (size_t)q * 8 * n_, &ldsB[0][(w * 32 + q * 8) * 64]);
    }
    __syncthreads();

    for (int it = 0; it < iters; ++it) {
        const unsigned short* La = (it & 1) ? &ldsA[1][0] : &ldsA[0][0];
        const unsigned short* Bb = (it & 1) ? &ldsB[1][0] : &ldsB[0][0];
        unsigned short* Sa = (it & 1) ? &ldsA[0][0] : &ldsA[1][0];
        unsigned short* Sb = (it & 1) ? &ldsB[0][0] : &ldsB[1][0];

        if (it + 1 < iters) {
            const int kofs = (it + 1) * 64;
            #pragma unroll
            for (int q = 0; q < 4; ++q) {
                gload16(gA + (size_t)q * 8 * IN_ + kofs, Sa + (w * 32 + q * 8) * 64);
                gload16(gB + (size_t)q * 8 * n_ + kofs, Sb + (w * 32 + q * 8) * 64);
            }
        }

        #pragma unroll
        for (int t2 = 0; t2 < 4; ++t2) {
            const int xs = (((t2 * 2 + lh) ^ l7) << 3);
            bf16x8 fa0 = *(const bf16x8*)&La[arow + xs];
            bf16x8 fa1 = *(const bf16x8*)&La[arow + 32 * 64 + xs];
            bf16x8 fb0 = *(const bf16x8*)&Bb[brow + xs];
            bf16x8 fb1 = *(const bf16x8*)&Bb[brow + 32 * 64 + xs];
            a00 = __builtin_amdgcn_mfma_f32_32x32x16_bf16(fa0, fb0, a00, 0, 0, 0);
            a01 = __builtin_amdgcn_mfma_f32_32x32x16_bf16(fa0, fb1, a01, 0, 0, 0);
            a10 = __builtin_amdgcn_mfma_f32_32x32x16_bf16(fa1, fb0, a10, 0, 0, 0);
            a11 = __builtin_amdgcn_mfma_f32_32x32x16_bf16(fa1, fb1, a11, 0, 0, 0);
        }
        __syncthreads();
    }

    const int gcolb = noff + nt * 128 + wn * 64 + l31;
    float* po = pf + ((size_t)sk * 512 + (size_t)mt * 128 + wm * 64 + 4 * lh) * IN_;
    #pragma unroll
    for (int r = 0; r < 16; ++r) {
        int row = (r & 3) + 8 * (r >> 2);
        po[(size_t)row * IN_ + gcolb]           = a00[r];
        po[(size_t)row * IN_ + gcolb + 32]      = a01[r];
        po[(size_t)(row + 32) * IN_ + gcolb]    = a10[r];
        po[(size_t)(row + 32) * IN_ + gcolb+32] = a11[r];
    }
}

// ---------------- epilogue: partial+hi/lo add, relu*P/M, re-split ----------------
template<int LAYER>
__global__ void k_epi(const float* __restrict__ pf,
                      const float* __restrict__ Pv, const float* __restrict__ Mv,
                      unsigned short* __restrict__ Yhi, unsigned short* __restrict__ Ylo,
                      float* __restrict__ Yf) {
    int e = (blockIdx.x * 256 + threadIdx.x) * 4;
    int m = e >> 13, c = e & 8191;
    const float* p0 = pf + (size_t)m * IN_ + c;
    float4 vh0 = *(const float4*)(p0);
    float4 vl0 = *(const float4*)(p0 + (size_t)256 * IN_);
    float4 vh1 = *(const float4*)(p0 + (size_t)512 * IN_);
    float4 vl1 = *(const float4*)(p0 + (size_t)768 * IN_);
    float4 pv = *(const float4*)(Pv + c);
    float4 mv = *(const float4*)(Mv + c);
    float vs[4] = {vh0.x + vl0.x + vh1.x + vl1.x, vh0.y + vl0.y + vh1.y + vl1.y,
                   vh0.z + vl0.z + vh1.z + vl1.z, vh0.w + vl0.w + vh1.w + vl1.w};
    float pa[4] = {pv.x, pv.y, pv.z, pv.w};
    float ma[4] = {mv.x, mv.y, mv.z, mv.w};
    if (LAYER == 0) {
        short hv[4], lv[4];
        #pragma unroll
        for (int j = 0; j < 4; ++j) {
            float y = fmaxf(vs[j], 0.f) * pa[j] + fmaxf(-vs[j], 0.f) * ma[j];
            unsigned short hb = rne_bf16(y);
            float hf = __builtin_bit_cast(float, (unsigned int)hb << 16);
            hv[j] = (short)hb;
            lv[j] = (short)rne_bf16(y - hf);
        }
        short4v h = {hv[0], hv[1], hv[2], hv[3]};
        short4v lo = {lv[0], lv[1], lv[2], lv[3]};
        *(short4v*)(Yhi + (size_t)m * IN_ + c) = h;
        *(short4v*)(Ylo + (size_t)m * IN_ + c) = lo;
    } else {
        float ov[4];
        #pragma unroll
        for (int j = 0; j < 4; ++j)
            ov[j] = fmaxf(vs[j], 0.f) * pa[j] + fmaxf(-vs[j], 0.f) * ma[j];
        *(float4*)(Yf + (size_t)m * IN_ + c) = *(float4*)ov;
    }
}

// ---------------- sum over sequence ----------------
__global__ void k_sums(const float* __restrict__ X, float* __restrict__ Y) {
    int idx = blockIdx.x * 256 + threadIdx.x;
    int b = idx >> 13, n = idx & 8191;
    const float* p = X + (size_t)b * 8 * IN_ + n;
    float s = 0.f;
    #pragma unroll
    for (int q = 0; q < 8; ++q) s += p[(size_t)q * IN_];
    Y[idx] = s;
}

// ---------------- MLP split-K partial GEMM, v2 ----------------
// block: 64 h-cols x all 32 m. 4 waves; wave w owns m in [w*8, w*8+8).
// X chunk staged in LDS (reads broadcast -> conflict-free); W read once grid-wide.
// grid (H/64, K/CK). P[c][m][h] partial.
template<int CK>
__global__ __launch_bounds__(256) void k_mlp2(
    const float* __restrict__ X, const float* __restrict__ W,
    float* __restrict__ P, int K, int H)
{
    __shared__ float Xs[32][CK];
    const int tid = threadIdx.x, lane = tid & 63, w = tid >> 6;
    const int h = blockIdx.x * 64 + lane;
    const int c = blockIdx.y, k0 = c * CK;

    for (int i = tid * 4; i < 32 * CK; i += 1024) {
        int m = i / CK, kk = i % CK;
        *(float4*)&Xs[m][kk] = *(const float4*)(X + (size_t)m * K + k0 + kk);
    }
    __syncthreads();

    float acc[8];
    #pragma unroll
    for (int m = 0; m < 8; ++m) acc[m] = 0.f;

    const float* wp = W + (size_t)k0 * H + h;
    #pragma unroll 8
    for (int kk = 0; kk < CK; ++kk) {
        float wv = wp[(size_t)kk * H];
        #pragma unroll
        for (int m = 0; m < 8; ++m)
            acc[m] = fmaf(Xs[w * 8 + m][kk], wv, acc[m]);
    }

    #pragma unroll
    for (int m = 0; m < 8; ++m)
        P[((size_t)c * 32 + w * 8 + m) * H + h] = acc[m];
}

// ---------------- reduce partials + bias (+relu) ----------------
__global__ void k_reduce(const float* __restrict__ P, const float* __restrict__ bias,
                         float* __restrict__ Y, int NC, int MH, int H, int do_relu) {
    int idx = blockIdx.x * 256 + threadIdx.x;
    if (idx >= MH) return;
    float s = bias[idx % H];
    for (int c = 0; c < NC; ++c) s += P[(size_t)c * MH + idx];
    Y[idx] = do_relu ? fmaxf(s, 0.f) : s;
}

extern "C" void kernel_launch(void* const* d_in, const int* in_sizes, int n_in,
                              void* d_out, int out_size, void* d_ws, size_t ws_size,
                              hipStream_t stream) {
    const float* xs0  = (const float*)d_in[0];
    const float* xs1  = (const float*)d_in[1];
    const float* xs2  = (const float*)d_in[2];
    const float* L0   = (const float*)d_in[3];
    const float* L1   = (const float*)d_in[4];
    const float* L2   = (const float*)d_in[5];
    const float* Wc0  = (const float*)d_in[6];
    const float* Wc1  = (const float*)d_in[7];
    const float* Wc2  = (const float*)d_in[8];
    const float* W_in = (const float*)d_in[9];
    const float* b_in = (const float*)d_in[10];
    const float* W_h  = (const float*)d_in[11];
    const float* b_h  = (const float*)d_in[12];
    const float* W_out= (const float*)d_in[13];
    const float* b_out= (const float*)d_in[14];

    char* w = (char*)d_ws;
    float*          PM = (float*)w;           w += (size_t)4 * IN_ * 4;
    unsigned short* Lb = (unsigned short*)w;  w += (size_t)L_TOT * 2;
    unsigned short* Xs = (unsigned short*)w;  w += (size_t)512 * IN_ * 2;
    unsigned short* Ys = (unsigned short*)w;  w += (size_t)512 * IN_ * 2;
    float*          pf = (float*)w;           w += (size_t)2 * 512 * IN_ * 4;
    float*          xB = (float*)Xs;          // alias: Xs dead after layer-0 GEMM
    float*          hsum = (float*)w;         w += (size_t)32 * IN_ * 4;
    float*          p1 = (float*)w;           w += (size_t)32 * 32 * H_ * 4;
    float*          h1 = (float*)w;           w += (size_t)32 * H_ * 4;
    float*          p2 = (float*)w;           w += (size_t)8 * 32 * H_ * 4;
    float*          h2 = (float*)w;           w += (size_t)32 * H_ * 4;
    float*          p3 = (float*)w;           w += (size_t)8 * 32 * OUT_ * 4;

    k_prep<<<64, 256, 0, stream>>>(Wc0, Wc1, Wc2, PM);
    k_cvtL<<<24576, 256, 0, stream>>>(L0, L1, L2, Lb);
    k_splitX<<<2048, 256, 0, stream>>>(xs0, xs1, xs2, Xs, Xs + (size_t)256 * IN_);

    k_gemm<<<512, 256, 0, stream>>>(Xs, Lb, pf);
    k_epi<0><<<2048, 256, 0, stream>>>(pf, PM + 0 * IN_, PM + 1 * IN_,
                                       Ys, Ys + (size_t)256 * IN_, nullptr);
    k_gemm<<<512, 256, 0, stream>>>(Ys, Lb, pf);
    k_epi<1><<<2048, 256, 0, stream>>>(pf, PM + 2 * IN_, PM + 3 * IN_,
                                       nullptr, nullptr, xB);

    k_sums<<<1024, 256, 0, stream>>>(xB, hsum);

    {   // [32,8192]@[8192,1024]: grid (16 h-tiles, 32 k-chunks of 256)
        dim3 g(16, 32);
        k_mlp2<256><<<g, 256, 0, stream>>>(hsum, W_in, p1, IN_, H_);
        k_reduce<<<128, 256, 0, stream>>>(p1, b_in, h1, 32, 32 * H_, H_, 1);
    }
    {   // [32,1024]@[1024,1024]: grid (16, 8 chunks of 128)
        dim3 g(16, 8);
        k_mlp2<128><<<g, 256, 0, stream>>>(h1, W_h, p2, H_, H_);
        k_reduce<<<128, 256, 0, stream>>>(p2, b_h, h2, 8, 32 * H_, H_, 1);
    }
    {   // [32,1024]@[1024,256]: grid (4, 8 chunks of 128)
        dim3 g(4, 8);
        k_mlp2<128><<<g, 256, 0, stream>>>(h2, W_out, p3, H_, OUT_);
        k_reduce<<<32, 256, 0, stream>>>(p3, b_out, (float*)d_out, 8, 32 * OUT_, OUT_, 0);
    }
}

// Round 5
// 209.271 us; speedup vs baseline: 1.5732x; 1.5732x over previous
//
#include <hip/hip_runtime.h>
#include <hip/hip_bf16.h>

// SCNN round 5: conv pipeline unchanged; MLP rebuilt as BW-shaped split-K.
//  - k_mlp3: float4 W loads along h (copy-kernel shape), wave = m-group
//    (broadcast LDS X reads), 4 outstanding 16B loads/thread, grid >= 512
//  - k_reduce4: float4 partial reduction
//  - p1 aliases pf (free after conv epilogue) so ws footprint is unchanged

#define B_    32
#define S_    8
#define BS_   256
#define F_    4
#define IN_   8192
#define H_    1024
#define OUT_  256

#define L_TOT  25165824LL     // 2048^2 + 4096^2 + 2048^2
#define LOFF1  4194304LL
#define LOFF2  20971520LL

typedef __attribute__((ext_vector_type(8)))  short bf16x8;
typedef __attribute__((ext_vector_type(4)))  short short4v;
typedef __attribute__((ext_vector_type(16))) float f32x16;

typedef const __attribute__((address_space(1))) void* gas_ptr;
typedef __attribute__((address_space(3))) void* las_ptr;

__device__ __forceinline__ void gload16(const void* g, void* s) {
    __builtin_amdgcn_global_load_lds((gas_ptr)g, (las_ptr)s, 16, 0, 0);
}

__device__ __forceinline__ unsigned short rne_bf16(float f) {
    unsigned int u = __builtin_bit_cast(unsigned int, f);
    u += 0x7FFFu + ((u >> 16) & 1u);
    return (unsigned short)(u >> 16);
}

// ---------------- P/M from Wc ----------------
__global__ void k_prep(const float* __restrict__ Wc0, const float* __restrict__ Wc1,
                       const float* __restrict__ Wc2, float* __restrict__ PM) {
    int idx = blockIdx.x * 256 + threadIdx.x;
    if (idx >= 2 * IN_) return;
    int l = idx / IN_, n = idx % IN_;
    const float* Wc; int nb, j;
    if (n < 2048)      { Wc = Wc0; nb = 2048; j = n;        }
    else if (n < 6144) { Wc = Wc1; nb = 4096; j = n - 2048; }
    else               { Wc = Wc2; nb = 2048; j = n - 6144; }
    float p = 0.f, m = 0.f;
    #pragma unroll
    for (int f = 0; f < F_; ++f) {
        float w = Wc[(l * F_ + f) * nb + j];
        p += fmaxf(w, 0.f);
        m += fmaxf(-w, 0.f);
    }
    PM[(l * 2 + 0) * IN_ + n] = p;
    PM[(l * 2 + 1) * IN_ + n] = m;
}

// ---------------- L f32 -> bf16 (concat) ----------------
__global__ void k_cvtL(const float* __restrict__ L0, const float* __restrict__ L1,
                       const float* __restrict__ L2, unsigned short* __restrict__ Lb) {
    long long e = ((long long)blockIdx.x * 256 + threadIdx.x) * 4;
    if (e >= L_TOT) return;
    const float* src; long long off;
    if (e < LOFF1)      { src = L0; off = 0; }
    else if (e < LOFF2) { src = L1; off = LOFF1; }
    else                { src = L2; off = LOFF2; }
    float4 v = *(const float4*)(src + (e - off));
    short4v o;
    o.x = (short)rne_bf16(v.x); o.y = (short)rne_bf16(v.y);
    o.z = (short)rne_bf16(v.z); o.w = (short)rne_bf16(v.w);
    *(short4v*)(Lb + e) = o;
}

// ---------------- xs -> stacked hi/lo bf16 [512][8192] ----------------
__global__ void k_splitX(const float* __restrict__ x0, const float* __restrict__ x1,
                         const float* __restrict__ x2,
                         unsigned short* __restrict__ Xhi, unsigned short* __restrict__ Xlo) {
    int e = (blockIdx.x * 256 + threadIdx.x) * 4;
    int m = e >> 13, c = e & 8191;
    const float* src; int n, c0;
    if (c < 2048)      { src = x0; n = 2048; c0 = c; }
    else if (c < 6144) { src = x1; n = 4096; c0 = c - 2048; }
    else               { src = x2; n = 2048; c0 = c - 6144; }
    float4 v = *(const float4*)(src + (size_t)m * n + c0);
    float a[4] = {v.x, v.y, v.z, v.w};
    short hv[4], lv[4];
    #pragma unroll
    for (int i = 0; i < 4; ++i) {
        unsigned short hb = rne_bf16(a[i]);
        float hf = __builtin_bit_cast(float, (unsigned int)hb << 16);
        hv[i] = (short)hb;
        lv[i] = (short)rne_bf16(a[i] - hf);
    }
    short4v h = {hv[0], hv[1], hv[2], hv[3]};
    short4v l = {lv[0], lv[1], lv[2], lv[3]};
    *(short4v*)(Xhi + (size_t)m * IN_ + c) = h;
    *(short4v*)(Xlo + (size_t)m * IN_ + c) = l;
}

// ---------------- MFMA GEMM: pf[sk][512][8192] partial = Astk . Lb^T ----------------
__global__ __launch_bounds__(256, 2) void k_gemm(
    const unsigned short* __restrict__ Astk,   // [512][8192] stacked hi/lo
    const unsigned short* __restrict__ Lb,     // concat bf16 L
    float* __restrict__ pf)                    // [2][512][8192]
{
    __shared__ __attribute__((aligned(16))) unsigned short ldsA[2][128 * 64];
    __shared__ __attribute__((aligned(16))) unsigned short ldsB[2][128 * 64];

    const int bx = blockIdx.x;
    const int sk = bx & 1, t = bx >> 1;
    int n_, noff, mt, nt; long long loff;
    if (t < 64)       { mt = t >> 4;         nt = t & 15;        n_ = 2048; noff = 0;    loff = 0;     }
    else if (t < 192) { int u = t - 64;  mt = u >> 5; nt = u & 31; n_ = 4096; noff = 2048; loff = LOFF1; }
    else              { int u = t - 192; mt = u >> 4; nt = u & 15; n_ = 2048; noff = 6144; loff = LOFF2; }

    const int tid = threadIdx.x, l = tid & 63, w = tid >> 6;
    const int n2 = n_ >> 1, k0 = sk * n2, iters = n2 >> 6;

    const int srow = w * 32 + (l >> 3);
    const int cswz = ((l & 7) ^ (l >> 3)) << 3;   // ushort offset
    const unsigned short* gA = Astk + (size_t)(mt * 128 + srow) * IN_ + noff + k0 + cswz;
    const unsigned short* gB = Lb + loff + (size_t)(nt * 128 + srow) * n_ + k0 + cswz;

    const int l31 = l & 31, lh = l >> 5, l7 = l31 & 7;
    const int wm = w >> 1, wn = w & 1;
    const int arow = (wm * 64 + l31) * 64;
    const int brow = (wn * 64 + l31) * 64;

    f32x16 a00, a01, a10, a11;
    #pragma unroll
    for (int r = 0; r < 16; ++r) { a00[r] = 0.f; a01[r] = 0.f; a10[r] = 0.f; a11[r] = 0.f; }

    #pragma unroll
    for (int q = 0; q < 4; ++q) {
        gload16(gA + (size_t)q * 8 * IN_, &ldsA[0][(w * 32 + q * 8) * 64]);
        gload16(gB + (size_t)q * 8 * n_, &ldsB[0][(w * 32 + q * 8) * 64]);
    }
    __syncthreads();

    for (int it = 0; it < iters; ++it) {
        const unsigned short* La = (it & 1) ? &ldsA[1][0] : &ldsA[0][0];
        const unsigned short* Bb = (it & 1) ? &ldsB[1][0] : &ldsB[0][0];
        unsigned short* Sa = (it & 1) ? &ldsA[0][0] : &ldsA[1][0];
        unsigned short* Sb = (it & 1) ? &ldsB[0][0] : &ldsB[1][0];

        if (it + 1 < iters) {
            const int kofs = (it + 1) * 64;
            #pragma unroll
            for (int q = 0; q < 4; ++q) {
                gload16(gA + (size_t)q * 8 * IN_ + kofs, Sa + (w * 32 + q * 8) * 64);
                gload16(gB + (size_t)q * 8 * n_ + kofs, Sb + (w * 32 + q * 8) * 64);
            }
        }

        #pragma unroll
        for (int t2 = 0; t2 < 4; ++t2) {
            const int xs = (((t2 * 2 + lh) ^ l7) << 3);
            bf16x8 fa0 = *(const bf16x8*)&La[arow + xs];
            bf16x8 fa1 = *(const bf16x8*)&La[arow + 32 * 64 + xs];
            bf16x8 fb0 = *(const bf16x8*)&Bb[brow + xs];
            bf16x8 fb1 = *(const bf16x8*)&Bb[brow + 32 * 64 + xs];
            a00 = __builtin_amdgcn_mfma_f32_32x32x16_bf16(fa0, fb0, a00, 0, 0, 0);
            a01 = __builtin_amdgcn_mfma_f32_32x32x16_bf16(fa0, fb1, a01, 0, 0, 0);
            a10 = __builtin_amdgcn_mfma_f32_32x32x16_bf16(fa1, fb0, a10, 0, 0, 0);
            a11 = __builtin_amdgcn_mfma_f32_32x32x16_bf16(fa1, fb1, a11, 0, 0, 0);
        }
        __syncthreads();
    }

    const int gcolb = noff + nt * 128 + wn * 64 + l31;
    float* po = pf + ((size_t)sk * 512 + (size_t)mt * 128 + wm * 64 + 4 * lh) * IN_;
    #pragma unroll
    for (int r = 0; r < 16; ++r) {
        int row = (r & 3) + 8 * (r >> 2);
        po[(size_t)row * IN_ + gcolb]           = a00[r];
        po[(size_t)row * IN_ + gcolb + 32]      = a01[r];
        po[(size_t)(row + 32) * IN_ + gcolb]    = a10[r];
        po[(size_t)(row + 32) * IN_ + gcolb+32] = a11[r];
    }
}

// ---------------- epilogue: partial+hi/lo add, relu*P/M, re-split ----------------
template<int LAYER>
__global__ void k_epi(const float* __restrict__ pf,
                      const float* __restrict__ Pv, const float* __restrict__ Mv,
                      unsigned short* __restrict__ Yhi, unsigned short* __restrict__ Ylo,
                      float* __restrict__ Yf) {
    int e = (blockIdx.x * 256 + threadIdx.x) * 4;
    int m = e >> 13, c = e & 8191;
    const float* p0 = pf + (size_t)m * IN_ + c;
    float4 vh0 = *(const float4*)(p0);
    float4 vl0 = *(const float4*)(p0 + (size_t)256 * IN_);
    float4 vh1 = *(const float4*)(p0 + (size_t)512 * IN_);
    float4 vl1 = *(const float4*)(p0 + (size_t)768 * IN_);
    float4 pv = *(const float4*)(Pv + c);
    float4 mv = *(const float4*)(Mv + c);
    float vs[4] = {vh0.x + vl0.x + vh1.x + vl1.x, vh0.y + vl0.y + vh1.y + vl1.y,
                   vh0.z + vl0.z + vh1.z + vl1.z, vh0.w + vl0.w + vh1.w + vl1.w};
    float pa[4] = {pv.x, pv.y, pv.z, pv.w};
    float ma[4] = {mv.x, mv.y, mv.z, mv.w};
    if (LAYER == 0) {
        short hv[4], lv[4];
        #pragma unroll
        for (int j = 0; j < 4; ++j) {
            float y = fmaxf(vs[j], 0.f) * pa[j] + fmaxf(-vs[j], 0.f) * ma[j];
            unsigned short hb = rne_bf16(y);
            float hf = __builtin_bit_cast(float, (unsigned int)hb << 16);
            hv[j] = (short)hb;
            lv[j] = (short)rne_bf16(y - hf);
        }
        short4v h = {hv[0], hv[1], hv[2], hv[3]};
        short4v lo = {lv[0], lv[1], lv[2], lv[3]};
        *(short4v*)(Yhi + (size_t)m * IN_ + c) = h;
        *(short4v*)(Ylo + (size_t)m * IN_ + c) = lo;
    } else {
        float ov[4];
        #pragma unroll
        for (int j = 0; j < 4; ++j)
            ov[j] = fmaxf(vs[j], 0.f) * pa[j] + fmaxf(-vs[j], 0.f) * ma[j];
        *(float4*)(Yf + (size_t)m * IN_ + c) = *(float4*)ov;
    }
}

// ---------------- sum over sequence ----------------
__global__ void k_sums(const float* __restrict__ X, float* __restrict__ Y) {
    int idx = blockIdx.x * 256 + threadIdx.x;
    int b = idx >> 13, n = idx & 8191;
    const float* p = X + (size_t)b * 8 * IN_ + n;
    float s = 0.f;
    #pragma unroll
    for (int q = 0; q < 8; ++q) s += p[(size_t)q * IN_];
    Y[idx] = s;
}

// ---------------- MLP split-K partial GEMM, v3 (BW-shaped) ----------------
// Thread: float4 of W along h (16B coalesced), 8 m accs. Wave = one m-group
// (all 64 lanes broadcast-read the same Xs[m][kk]). 4 outstanding loads.
// grid: (H/256 h-tiles, K/KC chunks).  P[c][m][h] partial.
template<int KC>
__global__ __launch_bounds__(256) void k_mlp3(
    const float* __restrict__ X, const float* __restrict__ W,
    float* __restrict__ P, int K, int H)
{
    __shared__ float Xs[32][KC];
    const int tid = threadIdx.x;
    const int lane = tid & 63;            // h4 slot
    const int mg = tid >> 6;              // wave index = m-group (8 m)
    const int h = (blockIdx.x * 64 + lane) * 4;
    const int c = blockIdx.y, k0 = c * KC;

    for (int i = tid * 4; i < 32 * KC; i += 1024) {
        int m = i / KC, kk = i % KC;
        *(float4*)&Xs[m][kk] = *(const float4*)(X + (size_t)m * K + k0 + kk);
    }
    __syncthreads();

    float4 acc[8];
    #pragma unroll
    for (int m = 0; m < 8; ++m) acc[m] = {0.f, 0.f, 0.f, 0.f};

    const float* wp = W + (size_t)k0 * H + h;
    for (int kk = 0; kk < KC; kk += 4) {
        float4 w4[4];
        #pragma unroll
        for (int u = 0; u < 4; ++u)
            w4[u] = *(const float4*)(wp + (size_t)(kk + u) * H);
        #pragma unroll
        for (int m = 0; m < 8; ++m) {
            float4 xv = *(const float4*)&Xs[mg * 8 + m][kk];
            acc[m].x = fmaf(xv.x, w4[0].x, acc[m].x);
            acc[m].y = fmaf(xv.x, w4[0].y, acc[m].y);
            acc[m].z = fmaf(xv.x, w4[0].z, acc[m].z);
            acc[m].w = fmaf(xv.x, w4[0].w, acc[m].w);
            acc[m].x = fmaf(xv.y, w4[1].x, acc[m].x);
            acc[m].y = fmaf(xv.y, w4[1].y, acc[m].y);
            acc[m].z = fmaf(xv.y, w4[1].z, acc[m].z);
            acc[m].w = fmaf(xv.y, w4[1].w, acc[m].w);
            acc[m].x = fmaf(xv.z, w4[2].x, acc[m].x);
            acc[m].y = fmaf(xv.z, w4[2].y, acc[m].y);
            acc[m].z = fmaf(xv.z, w4[2].z, acc[m].z);
            acc[m].w = fmaf(xv.z, w4[2].w, acc[m].w);
            acc[m].x = fmaf(xv.w, w4[3].x, acc[m].x);
            acc[m].y = fmaf(xv.w, w4[3].y, acc[m].y);
            acc[m].z = fmaf(xv.w, w4[3].z, acc[m].z);
            acc[m].w = fmaf(xv.w, w4[3].w, acc[m].w);
        }
    }
    #pragma unroll
    for (int m = 0; m < 8; ++m)
        *(float4*)(P + ((size_t)c * 32 + mg * 8 + m) * H + h) = acc[m];
}

// ---------------- reduce partials + bias (+relu), float4 ----------------
__global__ void k_reduce4(const float* __restrict__ P, const float* __restrict__ bias,
                          float* __restrict__ Y, int NC, int MH4, int H, int do_relu) {
    int idx = blockIdx.x * 256 + threadIdx.x;   // float4 index
    if (idx >= MH4) return;
    int h0 = (idx * 4) % H;
    float4 s = *(const float4*)(bias + h0);
    for (int c = 0; c < NC; ++c) {
        float4 v = *(const float4*)(P + (size_t)c * MH4 * 4 + (size_t)idx * 4);
        s.x += v.x; s.y += v.y; s.z += v.z; s.w += v.w;
    }
    if (do_relu) {
        s.x = fmaxf(s.x, 0.f); s.y = fmaxf(s.y, 0.f);
        s.z = fmaxf(s.z, 0.f); s.w = fmaxf(s.w, 0.f);
    }
    *(float4*)(Y + (size_t)idx * 4) = s;
}

extern "C" void kernel_launch(void* const* d_in, const int* in_sizes, int n_in,
                              void* d_out, int out_size, void* d_ws, size_t ws_size,
                              hipStream_t stream) {
    const float* xs0  = (const float*)d_in[0];
    const float* xs1  = (const float*)d_in[1];
    const float* xs2  = (const float*)d_in[2];
    const float* L0   = (const float*)d_in[3];
    const float* L1   = (const float*)d_in[4];
    const float* L2   = (const float*)d_in[5];
    const float* Wc0  = (const float*)d_in[6];
    const float* Wc1  = (const float*)d_in[7];
    const float* Wc2  = (const float*)d_in[8];
    const float* W_in = (const float*)d_in[9];
    const float* b_in = (const float*)d_in[10];
    const float* W_h  = (const float*)d_in[11];
    const float* b_h  = (const float*)d_in[12];
    const float* W_out= (const float*)d_in[13];
    const float* b_out= (const float*)d_in[14];

    char* w = (char*)d_ws;
    float*          PM = (float*)w;           w += (size_t)4 * IN_ * 4;
    unsigned short* Lb = (unsigned short*)w;  w += (size_t)L_TOT * 2;
    unsigned short* Xs = (unsigned short*)w;  w += (size_t)512 * IN_ * 2;
    unsigned short* Ys = (unsigned short*)w;  w += (size_t)512 * IN_ * 2;
    float*          pf = (float*)w;           w += (size_t)2 * 512 * IN_ * 4;   // 32 MB
    float*          xB = (float*)Xs;          // alias: Xs dead after layer-0 GEMM
    float*          hsum = (float*)w;         w += (size_t)32 * IN_ * 4;
    float*          p1 = pf;                  // alias: pf free after k_epi<1> (16 MB used)
    float*          h1 = (float*)w;           w += (size_t)32 * H_ * 4;
    float*          p2 = (float*)w;           w += (size_t)32 * 32 * H_ * 4;    // 4 MB
    float*          h2 = (float*)w;           w += (size_t)32 * H_ * 4;
    float*          p3 = (float*)w;           w += (size_t)32 * 32 * OUT_ * 4;  // 1 MB

    k_prep<<<64, 256, 0, stream>>>(Wc0, Wc1, Wc2, PM);
    k_cvtL<<<24576, 256, 0, stream>>>(L0, L1, L2, Lb);
    k_splitX<<<2048, 256, 0, stream>>>(xs0, xs1, xs2, Xs, Xs + (size_t)256 * IN_);

    k_gemm<<<512, 256, 0, stream>>>(Xs, Lb, pf);
    k_epi<0><<<2048, 256, 0, stream>>>(pf, PM + 0 * IN_, PM + 1 * IN_,
                                       Ys, Ys + (size_t)256 * IN_, nullptr);
    k_gemm<<<512, 256, 0, stream>>>(Ys, Lb, pf);
    k_epi<1><<<2048, 256, 0, stream>>>(pf, PM + 2 * IN_, PM + 3 * IN_,
                                       nullptr, nullptr, xB);

    k_sums<<<1024, 256, 0, stream>>>(xB, hsum);

    {   // [32,8192]@[8192,1024]: grid (4 h-tiles, 128 k-chunks of 64)
        dim3 g(4, 128);
        k_mlp3<64><<<g, 256, 0, stream>>>(hsum, W_in, p1, IN_, H_);
        k_reduce4<<<32, 256, 0, stream>>>(p1, b_in, h1, 128, 8192, H_, 1);
    }
    {   // [32,1024]@[1024,1024]: grid (4, 32 chunks of 32)
        dim3 g(4, 32);
        k_mlp3<32><<<g, 256, 0, stream>>>(h1, W_h, p2, H_, H_);
        k_reduce4<<<32, 256, 0, stream>>>(p2, b_h, h2, 32, 8192, H_, 1);
    }
    {   // [32,1024]@[1024,256]: grid (1, 32 chunks of 32)
        dim3 g(1, 32);
        k_mlp3<32><<<g, 256, 0, stream>>>(h2, W_out, p3, H_, OUT_);
        k_reduce4<<<8, 256, 0, stream>>>(p3, b_out, (float*)d_out, 32, 2048, OUT_, 0);
    }
}